// Round 6
// baseline (1865.784 us; speedup 1.0000x reference)
//
#include <hip/hip_runtime.h>
#include <hip/hip_fp16.h>
#include <cstdint>
#include <cstddef>

// Problem constants: B=64, T=512, D=256, H=512
#define T_STEPS 512
#define D_DIM 256
#define H_DIM 512
#define B_SZ 64

// Scan: ONE workgroup per batch row, 1024 threads (16 waves, 4/SIMD, 128
// VGPR cap). Full Wh on-CU as packed f16: 92 half2 pairs/thread in REGISTERS
// (23 explicit uint4 SSA locals — NOT an array, so promote-alloca can't
// demote them to scratch like round 5 did; VGPR_Count=64 + 2.7us/step L2
// scratch reload was the r5 failure) + 36 pairs/thread in LDS (144 KB).
// Column c = tid&511, k-half kh = tid>>9. All sync is intra-CU barriers.
#define NTH5 1024
#define WREG 92            // half2 pairs per thread in registers (23 uint4)
#define WLDS 18            // uint2 rows in LDS: 92 + 2*18 = 128 pairs total

// ---------------------------------------------------------------------------
// Kernel 1: xproj = inputs @ Wx + bias  ->  d_out  [B*T, H]   (unchanged)
// ---------------------------------------------------------------------------
#define BM 64
#define BN 128
#define BK 32

__global__ __launch_bounds__(256)
void xproj_gemm(const float* __restrict__ A, const float* __restrict__ Bm,
                const float* __restrict__ bias, float* __restrict__ C,
                int M, int N, int K) {
    __shared__ float As[BK][BM];
    __shared__ float Bs[BK][BN];

    const int tid = threadIdx.x;
    const int tx = tid & 15;
    const int ty = tid >> 4;
    const int row0 = blockIdx.y * BM;
    const int col0 = blockIdx.x * BN;

    float acc[4][8];
    #pragma unroll
    for (int i = 0; i < 4; ++i)
        #pragma unroll
        for (int j = 0; j < 8; ++j) acc[i][j] = 0.0f;

    for (int kt = 0; kt < K; kt += BK) {
        #pragma unroll
        for (int i = 0; i < 2; ++i) {
            int q  = tid + i * 256;
            int m  = q >> 3;
            int k4 = (q & 7) << 2;
            float4 v = *(const float4*)&A[(size_t)(row0 + m) * K + kt + k4];
            As[k4 + 0][m] = v.x; As[k4 + 1][m] = v.y;
            As[k4 + 2][m] = v.z; As[k4 + 3][m] = v.w;
        }
        #pragma unroll
        for (int i = 0; i < 4; ++i) {
            int q  = tid + i * 256;
            int kk = q >> 5;
            int n4 = (q & 31) << 2;
            *(float4*)&Bs[kk][n4] = *(const float4*)&Bm[(size_t)(kt + kk) * N + col0 + n4];
        }
        __syncthreads();
        #pragma unroll
        for (int k = 0; k < BK; ++k) {
            float4 a  = *(const float4*)&As[k][ty << 2];
            float4 b0 = *(const float4*)&Bs[k][tx << 2];
            float4 b1 = *(const float4*)&Bs[k][(tx << 2) + 64];
            float av[4] = {a.x, a.y, a.z, a.w};
            float bv[8] = {b0.x, b0.y, b0.z, b0.w, b1.x, b1.y, b1.z, b1.w};
            #pragma unroll
            for (int i = 0; i < 4; ++i)
                #pragma unroll
                for (int j = 0; j < 8; ++j)
                    acc[i][j] = fmaf(av[i], bv[j], acc[i][j]);
        }
        __syncthreads();
    }

    float bv0[4], bv1[4];
    #pragma unroll
    for (int j = 0; j < 4; ++j) {
        bv0[j] = bias[col0 + (tx << 2) + j];
        bv1[j] = bias[col0 + (tx << 2) + 64 + j];
    }
    #pragma unroll
    for (int i = 0; i < 4; ++i) {
        int r = row0 + (ty << 2) + i;
        float4 o0 = make_float4(acc[i][0] + bv0[0], acc[i][1] + bv0[1],
                                acc[i][2] + bv0[2], acc[i][3] + bv0[3]);
        float4 o1 = make_float4(acc[i][4] + bv1[0], acc[i][5] + bv1[1],
                                acc[i][6] + bv1[2], acc[i][7] + bv1[3]);
        *(float4*)&C[(size_t)r * N + col0 + (tx << 2)]      = o0;
        *(float4*)&C[(size_t)r * N + col0 + (tx << 2) + 64] = o1;
    }
}

// ---------------------------------------------------------------------------
// Kernel 2: the scan, fully CU-local.
// ---------------------------------------------------------------------------
typedef _Float16 half2v __attribute__((ext_vector_type(2)));

__device__ __forceinline__ float fdot2u(unsigned int a, unsigned int b, float c) {
    // v_dot2_f32_f16: a.lo*b.lo + a.hi*b.hi + c
    return __builtin_amdgcn_fdot2(__builtin_bit_cast(half2v, a),
                                  __builtin_bit_cast(half2v, b), c, false);
}

__device__ __forceinline__ unsigned int pack_h2(float lo, float hi) {
    __half2 h = __floats2half2_rn(lo, hi);   // .x = lo (low 16 bits)
    return __builtin_bit_cast(unsigned int, h);
}

__device__ __forceinline__ float tanh_fast(float x) {
    float ax = fabsf(x);
    float e  = __expf(2.0f * ax);
    float t  = 1.0f - 2.0f / (e + 1.0f);
    return copysignf(t, x);
}

// 23 register uint4s: pairs 4q..4q+3, pair j = Wh rows (kh*256+2j, +2j+1)
#define FORALL23(F) F(0) F(1) F(2) F(3) F(4) F(5) F(6) F(7) F(8) F(9) F(10) \
    F(11) F(12) F(13) F(14) F(15) F(16) F(17) F(18) F(19) F(20) F(21) F(22)

__global__ __launch_bounds__(NTH5, 4)   // 4 waves/EU -> 128 VGPR cap
void rnn_scan6(const float* __restrict__ Wh, const float* __restrict__ h0,
               const float* __restrict__ gamma, const float* __restrict__ beta,
               float* __restrict__ out) {
    const int r   = blockIdx.x;                // batch row
    const int tid = threadIdx.x;               // 0..1023
    const int c   = tid & (H_DIM - 1);         // column 0..511
    const int kh  = tid >> 9;                  // k-half 0/1 (wave-uniform)

    __shared__ uint2 wl2[WLDS][NTH5];                  // 144 KB weight slab
    __shared__ __align__(16) __half hh_s[H_DIM];       // h state, f16
    __shared__ float part_s[NTH5];                     // k-split partials
    __shared__ float wred_s[16];                       // LN wave partials

    const float* wcol = Wh + (size_t)(kh * 256) * H_DIM + c;

#define DECLW(q) uint4 wr##q;
    FORALL23(DECLW)
#undef DECLW
#define LOADW(q) { const float* wp = wcol + (size_t)(8 * q) * H_DIM;          \
        wr##q.x = pack_h2(wp[0],                  wp[(size_t)1 * H_DIM]);     \
        wr##q.y = pack_h2(wp[(size_t)2 * H_DIM],  wp[(size_t)3 * H_DIM]);     \
        wr##q.z = pack_h2(wp[(size_t)4 * H_DIM],  wp[(size_t)5 * H_DIM]);     \
        wr##q.w = pack_h2(wp[(size_t)6 * H_DIM],  wp[(size_t)7 * H_DIM]); }
    FORALL23(LOADW)
#undef LOADW

    // LDS tail: pairs j0=WREG+2p and j0+1 for p in [0,18)
    #pragma unroll
    for (int p = 0; p < WLDS; ++p) {
        int j0 = WREG + 2 * p;
        const float* wp = wcol + (size_t)(2 * j0) * H_DIM;
        wl2[p][tid] = make_uint2(
            pack_h2(wp[0],                 wp[(size_t)1 * H_DIM]),
            pack_h2(wp[(size_t)2 * H_DIM], wp[(size_t)3 * H_DIM]));
    }

    if (tid < H_DIM) hh_s[tid] = __float2half_rn(h0[r * H_DIM + tid]);
    const float g_own = (tid < H_DIM) ? gamma[tid] : 0.0f;
    const float b_own = (tid < H_DIM) ? beta[tid]  : 0.0f;
    float* outrow = out + (size_t)r * T_STEPS * H_DIM;
    __syncthreads();

    for (int t = 0; t < T_STEPS; ++t) {
        // xp prefetch for own column (consumed after the GEMM)
        float xp = (tid < H_DIM) ? outrow[t * H_DIM + tid] : 0.0f;

        // partial dot over this thread's 256-k half (f16 dot2, h broadcast)
        const uint4* hu4 = ((const uint4*)hh_s) + kh * 32;               // pairs 0..91
        const uint2* hu2 = ((const uint2*)hh_s) + kh * 64 + (WREG >> 1); // pairs 92..
        float acc = 0.0f;
#define DOT4(q) { uint4 hv = hu4[q];                 \
        acc = fdot2u(wr##q.x, hv.x, acc);            \
        acc = fdot2u(wr##q.y, hv.y, acc);            \
        acc = fdot2u(wr##q.z, hv.z, acc);            \
        acc = fdot2u(wr##q.w, hv.w, acc); }
        FORALL23(DOT4)
#undef DOT4
        #pragma unroll
        for (int p = 0; p < WLDS; ++p) {            // 18 x uint2 = 36 pairs
            uint2 wv = wl2[p][tid];
            uint2 hv = hu2[p];
            acc = fdot2u(wv.x, hv.x, acc);
            acc = fdot2u(wv.y, hv.y, acc);
        }
        part_s[tid] = acc;
        __syncthreads();                            // B1: partials ready

        // combine k-halves + xp; LN stats over the 512 columns
        float z = 0.0f, s = 0.0f, q = 0.0f;
        if (tid < H_DIM) {
            z = part_s[tid] + part_s[tid + H_DIM] + xp;
            s = z; q = z * z;
        }
        #pragma unroll
        for (int o = 32; o > 0; o >>= 1) {
            s += __shfl_down(s, o, 64);
            q += __shfl_down(q, o, 64);
        }
        if (tid < H_DIM && (tid & 63) == 0) {
            wred_s[tid >> 6]       = s;
            wred_s[8 + (tid >> 6)] = q;
        }
        __syncthreads();                            // B2: stats ready
        float S = 0.0f, Q = 0.0f;
        #pragma unroll
        for (int i = 0; i < 8; ++i) { S += wred_s[i]; Q += wred_s[8 + i]; }
        float mean = S * (1.0f / H_DIM);
        float var  = Q * (1.0f / H_DIM) - mean * mean;
        float rstd = rsqrtf(var + 1e-3f);           // keras LN eps

        if (tid < H_DIM) {
            float hn = tanh_fast((z - mean) * rstd * g_own + b_own);
            outrow[t * H_DIM + tid] = hn;           // overwrite xproj slot
            hh_s[tid] = __float2half_rn(hn);        // safe: reads ended pre-B1
        }
        __syncthreads();                            // B3: h ready for t+1
    }
}

// ---------------------------------------------------------------------------
extern "C" void kernel_launch(void* const* d_in, const int* in_sizes, int n_in,
                              void* d_out, int out_size, void* d_ws, size_t ws_size,
                              hipStream_t stream) {
    const float* inputs = (const float*)d_in[0];  // [B,T,D]
    const float* h0     = (const float*)d_in[1];  // [B,H]
    const float* Wx     = (const float*)d_in[2];  // [D,H]
    const float* Wh     = (const float*)d_in[3];  // [H,H]
    const float* bias   = (const float*)d_in[4];  // [H]
    const float* gamma  = (const float*)d_in[5];  // [H]
    const float* beta   = (const float*)d_in[6];  // [H]
    float* out = (float*)d_out;                   // [B,T,H]

    const int M = B_SZ * T_STEPS;                 // 32768
    dim3 g1(H_DIM / BN, M / BM);                  // (4, 512)
    xproj_gemm<<<g1, 256, 0, stream>>>(inputs, Wx, bias, out, M, H_DIM, D_DIM);

    rnn_scan6<<<B_SZ, NTH5, 0, stream>>>(Wh, h0, gamma, beta, out);
}